// Round 4
// baseline (953.896 us; speedup 1.0000x reference)
//
#include <hip/hip_runtime.h>
#include <stdint.h>

typedef unsigned short u16;
typedef __attribute__((ext_vector_type(8))) __bf16 bf16x8;
typedef __attribute__((ext_vector_type(4))) float f32x4;

// ---- problem constants ----
#define M_TOT   16384      // BATCH*SEQ
#define K1      4096
#define N1_PAD  1920       // 1856 padded to 15*128
#define N1_REAL 1856

// FWD[h] = j such that INVERSE_INDICES[j] == h  (computed head h -> output head j)
__constant__ int c_FWD[32] = {3,1,7,9,11,12,15,17,19,21,22,4,14,8,23,25,
                              16,27,6,2,18,28,29,26,30,5,0,20,31,13,10,24};
__constant__ int c_OFF[8]  = {0,384,704,960,1216,1408,1600,1728};
__constant__ int c_RANK[8] = {384,320,256,256,192,192,128,128};

__device__ __forceinline__ u16 f2bf(float x) {
  unsigned int u = __builtin_bit_cast(unsigned int, x);
  u += 0x7fffu + ((u >> 16) & 1u);   // RNE truncate f32 -> bf16
  return (u16)(u >> 16);
}

__device__ __forceinline__ void gload_lds16(const u16* g, u16* l) {
  __builtin_amdgcn_global_load_lds(
      (const __attribute__((address_space(1))) unsigned int*)g,
      (__attribute__((address_space(3))) unsigned int*)l, 16, 0, 0);
}

// ---- f32 -> bf16 flat convert (one float4 per thread) ----
__global__ void cvt_f32_bf16(const float* __restrict__ src, u16* __restrict__ dst, int n4) {
  int i = blockIdx.x * blockDim.x + threadIdx.x;
  if (i >= n4) return;
  float4 v = reinterpret_cast<const float4*>(src)[i];
  uint64_t pack = (uint64_t)f2bf(v.x) | ((uint64_t)f2bf(v.y) << 16) |
                  ((uint64_t)f2bf(v.z) << 32) | ((uint64_t)f2bf(v.w) << 48);
  reinterpret_cast<uint64_t*>(dst)[i] = pack;
}

// ---- VT_w [1856][4096] f32 -> [1920][4096] bf16, zero-padded rows ----
__global__ void cvt_pad_vt(const float* __restrict__ src, u16* __restrict__ dst) {
  int i = blockIdx.x * blockDim.x + threadIdx.x;   // one float4
  if (i >= (N1_PAD * K1 / 4)) return;
  int row = i >> 10;                               // 1024 float4 per row
  uint64_t pack = 0;
  if (row < N1_REAL) {
    float4 v = reinterpret_cast<const float4*>(src)[i];
    pack = (uint64_t)f2bf(v.x) | ((uint64_t)f2bf(v.y) << 16) |
           ((uint64_t)f2bf(v.z) << 32) | ((uint64_t)f2bf(v.w) << 48);
  }
  reinterpret_cast<uint64_t*>(dst)[i] = pack;
}

// ---- pack all 8 U_w (f32 -> bf16, contiguous) + gather all 8 biases, one launch ----
struct GroupPtrs { const float* uw[8]; const float* ub[8]; };

__global__ void pack_u_bias(GroupPtrs gp, u16* __restrict__ ub, float* __restrict__ bias) {
  const int g = blockIdx.y;
  const int rank = c_RANK[g];
  const int n4 = (512 * rank) >> 2;                 // float4 count for this group
  const int idx = blockIdx.x * blockDim.x + threadIdx.x;
  if (idx < n4) {
    float4 v = reinterpret_cast<const float4*>(gp.uw[g])[idx];
    uint64_t pack = (uint64_t)f2bf(v.x) | ((uint64_t)f2bf(v.y) << 16) |
                    ((uint64_t)f2bf(v.z) << 32) | ((uint64_t)f2bf(v.w) << 48);
    reinterpret_cast<uint64_t*>(ub + (size_t)512 * c_OFF[g])[idx] = pack;
  }
  if (blockIdx.x == 0 && idx < 128) {               // 512 floats = 128 float4
    reinterpret_cast<float4*>(bias + (g << 9))[idx] =
        reinterpret_cast<const float4*>(gp.ub[g])[idx];
  }
}

// ============ GEMM1: latents[M][1920](bf16) = hs[M][4096] @ VT[1920][4096]^T ============
// m97 structure: 128x128 tile, BK=64, 4 waves each 64x64 (4x4 frags of 16x16x32),
// global_load_lds width 16, linear LDS, 2 barriers per K-step.
__global__ void gemm1_kernel(const u16* __restrict__ A, const u16* __restrict__ B,
                             u16* __restrict__ C) {
  __shared__ u16 lA[128 * 64];
  __shared__ u16 lB[128 * 64];
  const int tid  = threadIdx.x;
  const int wave = tid >> 6, lane = tid & 63;
  const int lr = lane & 15, lk = lane >> 4;
  const int wm = wave >> 1, wn = wave & 1;
  const int row0 = blockIdx.y * 128;
  const int col0 = blockIdx.x * 128;

  const u16* Ab = A + (size_t)row0 * K1;
  const u16* Bb = B + (size_t)col0 * K1;

  f32x4 acc[4][4] = {};

  for (int kt = 0; kt < K1 / 64; ++kt) {
    __syncthreads();
#pragma unroll
    for (int q = 0; q < 4; ++q) {
      int ci = q * 256 + tid;            // 16B chunk index, 0..1023
      int r = ci >> 3, c = ci & 7;
      int ldst = (q * 256 + wave * 64) * 8;   // uniform per wave (elems)
      gload_lds16(Ab + (size_t)r * K1 + kt * 64 + c * 8, lA + ldst);
      gload_lds16(Bb + (size_t)r * K1 + kt * 64 + c * 8, lB + ldst);
    }
    __syncthreads();
#pragma unroll
    for (int kk = 0; kk < 2; ++kk) {
      bf16x8 af[4], bfr[4];
#pragma unroll
      for (int m = 0; m < 4; ++m)
        af[m] = *reinterpret_cast<const bf16x8*>(&lA[(wm * 64 + m * 16 + lr) * 64 + kk * 32 + lk * 8]);
#pragma unroll
      for (int n = 0; n < 4; ++n)
        bfr[n] = *reinterpret_cast<const bf16x8*>(&lB[(wn * 64 + n * 16 + lr) * 64 + kk * 32 + lk * 8]);
#pragma unroll
      for (int m = 0; m < 4; ++m)
#pragma unroll
        for (int n = 0; n < 4; ++n)
          acc[m][n] = __builtin_amdgcn_mfma_f32_16x16x32_bf16(af[m], bfr[n], acc[m][n], 0, 0, 0);
    }
  }

  // epilogue: C/D layout col=lane&15, row=(lane>>4)*4+reg (m89-verified)
#pragma unroll
  for (int n = 0; n < 4; ++n) {
    int col = col0 + wn * 64 + n * 16 + lr;
#pragma unroll
    for (int m = 0; m < 4; ++m) {
#pragma unroll
      for (int v = 0; v < 4; ++v) {
        int row = row0 + wm * 64 + m * 16 + lk * 4 + v;
        C[(size_t)row * N1_PAD + col] = f2bf(acc[m][n][v]);
      }
    }
  }
}

// ============ GEMM2: grouped, out[M][4096](f32) with bias + head permutation ============
__global__ void gemm2_kernel(const u16* __restrict__ A,      // latents [M][1920]
                             const u16* __restrict__ Uall,   // packed [512][r_g] per group
                             const float* __restrict__ bias, // [8][512]
                             float* __restrict__ out) {      // [M][4096]
  const int g = blockIdx.z;
  const int rank = c_RANK[g], off = c_OFF[g];
  __shared__ u16 lA[128 * 64];
  __shared__ u16 lB[128 * 64];
  const int tid  = threadIdx.x;
  const int wave = tid >> 6, lane = tid & 63;
  const int lr = lane & 15, lk = lane >> 4;
  const int wm = wave >> 1, wn = wave & 1;
  const int row0 = blockIdx.y * 128;
  const int col0 = blockIdx.x * 128;        // within the group's 512 cols

  const u16* Ab = A + (size_t)row0 * N1_PAD + off;
  const u16* Bb = Uall + (size_t)512 * off + (size_t)col0 * rank;

  f32x4 acc[4][4] = {};

  const int nkt = rank >> 6;
  for (int kt = 0; kt < nkt; ++kt) {
    __syncthreads();
#pragma unroll
    for (int q = 0; q < 4; ++q) {
      int ci = q * 256 + tid;
      int r = ci >> 3, c = ci & 7;
      int ldst = (q * 256 + wave * 64) * 8;
      gload_lds16(Ab + (size_t)r * N1_PAD + kt * 64 + c * 8, lA + ldst);
      gload_lds16(Bb + (size_t)r * rank   + kt * 64 + c * 8, lB + ldst);
    }
    __syncthreads();
#pragma unroll
    for (int kk = 0; kk < 2; ++kk) {
      bf16x8 af[4], bfr[4];
#pragma unroll
      for (int m = 0; m < 4; ++m)
        af[m] = *reinterpret_cast<const bf16x8*>(&lA[(wm * 64 + m * 16 + lr) * 64 + kk * 32 + lk * 8]);
#pragma unroll
      for (int n = 0; n < 4; ++n)
        bfr[n] = *reinterpret_cast<const bf16x8*>(&lB[(wn * 64 + n * 16 + lr) * 64 + kk * 32 + lk * 8]);
#pragma unroll
      for (int m = 0; m < 4; ++m)
#pragma unroll
        for (int n = 0; n < 4; ++n)
          acc[m][n] = __builtin_amdgcn_mfma_f32_16x16x32_bf16(af[m], bfr[n], acc[m][n], 0, 0, 0);
    }
  }

#pragma unroll
  for (int n = 0; n < 4; ++n) {
    int cg = col0 + wn * 64 + n * 16 + lr;          // 0..511 within group
    int h  = (g << 2) + (cg >> 7);                  // computed head
    int oc = (c_FWD[h] << 7) | (cg & 127);          // permuted output column
    float bv = bias[(g << 9) + cg];
#pragma unroll
    for (int m = 0; m < 4; ++m) {
#pragma unroll
      for (int v = 0; v < 4; ++v) {
        int row = row0 + wm * 64 + m * 16 + lk * 4 + v;
        out[(size_t)row * 4096 + oc] = acc[m][n][v] + bv;
      }
    }
  }
}

extern "C" void kernel_launch(void* const* d_in, const int* in_sizes, int n_in,
                              void* d_out, int out_size, void* d_ws, size_t ws_size,
                              hipStream_t stream) {
  const float* hs = (const float*)d_in[0];
  const float* vt = (const float*)d_in[1];

  // workspace layout (all 16B-aligned); total ~205 MiB
  u16* hsb = (u16*)d_ws;                                // [16384][4096] bf16: 128 MiB
  u16* vtb = hsb + (size_t)M_TOT * K1;                  // [1920][4096]  bf16: 15 MiB
  u16* lat = vtb + (size_t)N1_PAD * K1;                 // [16384][1920] bf16: 60 MiB
  u16* ub  = lat + (size_t)M_TOT * N1_PAD;              // packed U: [512][r_g] x8: 1.9 MiB
  float* bias = (float*)(ub + (size_t)512 * N1_REAL);   // [8][512] f32

  // 1) convert hidden_states to bf16
  {
    int n4 = M_TOT * K1 / 4;  // 16,777,216 float4s
    cvt_f32_bf16<<<n4 / 256, 256, 0, stream>>>(hs, hsb, n4);
  }
  // 2) convert + zero-pad VT_w
  {
    int n4 = N1_PAD * K1 / 4;
    cvt_pad_vt<<<(n4 + 255) / 256, 256, 0, stream>>>(vt, vtb);
  }
  // 3) pack all U_w + biases in one launch
  {
    GroupPtrs gp;
    for (int g = 0; g < 8; ++g) {
      gp.uw[g] = (const float*)d_in[2 + 2 * g];
      gp.ub[g] = (const float*)d_in[3 + 2 * g];
    }
    // max group: 512*384/4 = 49152 float4 -> 192 blocks of 256
    pack_u_bias<<<dim3(192, 8), 256, 0, stream>>>(gp, ub, bias);
  }

  // 4) GEMM1: latents = hs @ VT^T   (grid: 15 N-tiles x 128 M-tiles)
  gemm1_kernel<<<dim3(N1_PAD / 128, M_TOT / 128), 256, 0, stream>>>(hsb, vtb, lat);

  // 5) GEMM2: grouped low-rank up-proj + bias + head permutation
  gemm2_kernel<<<dim3(4, M_TOT / 128, 8), 256, 0, stream>>>(lat, ub, bias, (float*)d_out);
}

// Round 7
// 838.661 us; speedup vs baseline: 1.1374x; 1.1374x over previous
//
#include <hip/hip_runtime.h>
#include <stdint.h>

typedef unsigned short u16;
typedef __attribute__((ext_vector_type(8))) __bf16 bf16x8;
typedef __attribute__((ext_vector_type(4))) float f32x4;

// ---- problem constants ----
#define M_TOT   16384      // BATCH*SEQ
#define K1      4096
#define N1_PAD  1920       // 1856 padded to 15*128
#define N1_REAL 1856

// FWD[h] = j such that INVERSE_INDICES[j] == h  (computed head h -> output head j)
__constant__ int c_FWD[32] = {3,1,7,9,11,12,15,17,19,21,22,4,14,8,23,25,
                              16,27,6,2,18,28,29,26,30,5,0,20,31,13,10,24};
__constant__ int c_OFF[8]  = {0,384,704,960,1216,1408,1600,1728};
__constant__ int c_RANK[8] = {384,320,256,256,192,192,128,128};

__device__ __forceinline__ u16 f2bf(float x) {
  unsigned int u = __builtin_bit_cast(unsigned int, x);
  u += 0x7fffu + ((u >> 16) & 1u);   // RNE truncate f32 -> bf16
  return (u16)(u >> 16);
}

__device__ __forceinline__ void gload_lds16(const u16* g, u16* l) {
  __builtin_amdgcn_global_load_lds(
      (const __attribute__((address_space(1))) unsigned int*)g,
      (__attribute__((address_space(3))) unsigned int*)l, 16, 0, 0);
}

// ---- f32 -> bf16 flat convert (one float4 per thread) ----
__global__ void cvt_f32_bf16(const float* __restrict__ src, u16* __restrict__ dst, int n4) {
  int i = blockIdx.x * blockDim.x + threadIdx.x;
  if (i >= n4) return;
  float4 v = reinterpret_cast<const float4*>(src)[i];
  uint64_t pack = (uint64_t)f2bf(v.x) | ((uint64_t)f2bf(v.y) << 16) |
                  ((uint64_t)f2bf(v.z) << 32) | ((uint64_t)f2bf(v.w) << 48);
  reinterpret_cast<uint64_t*>(dst)[i] = pack;
}

// ---- VT_w [1856][4096] f32 -> [1920][4096] bf16, zero-padded rows ----
__global__ void cvt_pad_vt(const float* __restrict__ src, u16* __restrict__ dst) {
  int i = blockIdx.x * blockDim.x + threadIdx.x;   // one float4
  if (i >= (N1_PAD * K1 / 4)) return;
  int row = i >> 10;                               // 1024 float4 per row
  uint64_t pack = 0;
  if (row < N1_REAL) {
    float4 v = reinterpret_cast<const float4*>(src)[i];
    pack = (uint64_t)f2bf(v.x) | ((uint64_t)f2bf(v.y) << 16) |
           ((uint64_t)f2bf(v.z) << 32) | ((uint64_t)f2bf(v.w) << 48);
  }
  reinterpret_cast<uint64_t*>(dst)[i] = pack;
}

// ---- pack all 8 U_w (f32 -> bf16, contiguous) + gather all 8 biases, one launch ----
struct GroupPtrs { const float* uw[8]; const float* ub[8]; };

__global__ void pack_u_bias(GroupPtrs gp, u16* __restrict__ ub, float* __restrict__ bias) {
  const int g = blockIdx.y;
  const int rank = c_RANK[g];
  const int n4 = (512 * rank) >> 2;                 // float4 count for this group
  const int idx = blockIdx.x * blockDim.x + threadIdx.x;
  if (idx < n4) {
    float4 v = reinterpret_cast<const float4*>(gp.uw[g])[idx];
    uint64_t pack = (uint64_t)f2bf(v.x) | ((uint64_t)f2bf(v.y) << 16) |
                    ((uint64_t)f2bf(v.z) << 32) | ((uint64_t)f2bf(v.w) << 48);
    reinterpret_cast<uint64_t*>(ub + (size_t)512 * c_OFF[g])[idx] = pack;
  }
  if (blockIdx.x == 0 && idx < 128) {               // 512 floats = 128 float4
    reinterpret_cast<float4*>(bias + (g << 9))[idx] =
        reinterpret_cast<const float4*>(gp.ub[g])[idx];
  }
}

// ============ GEMM1: latents[M][1920](bf16) = hs[M][4096] @ VT[1920][4096]^T ============
// m97 structure + XCD-chunked remap (T1): each XCD owns a contiguous 16-M-tile
// chunk, N varies fastest within the chunk -> A-panel and B-panels stay in the
// XCD's private L2 instead of re-fetching from HBM (round-4 FETCH was 8.7x ideal).
__global__ void gemm1_kernel(const u16* __restrict__ A, const u16* __restrict__ B,
                             u16* __restrict__ C) {
  __shared__ u16 lA[128 * 64];
  __shared__ u16 lB[128 * 64];
  const int tid  = threadIdx.x;
  const int wave = tid >> 6, lane = tid & 63;
  const int lr = lane & 15, lk = lane >> 4;
  const int wm = wave >> 1, wn = wave & 1;

  // XCD-chunked bijection: 1920 wgs = 8 xcds * (16 M-tiles * 15 N-tiles)
  const int W   = blockIdx.x;
  const int xcd = W & 7, idx = W >> 3;     // idx 0..239
  const int mt  = (idx / 15) + xcd * 16;   // 0..127
  const int nt  = idx % 15;                // 0..14
  const int row0 = mt * 128;
  const int col0 = nt * 128;

  const u16* Ab = A + (size_t)row0 * K1;
  const u16* Bb = B + (size_t)col0 * K1;

  f32x4 acc[4][4] = {};

  for (int kt = 0; kt < K1 / 64; ++kt) {
    __syncthreads();
#pragma unroll
    for (int q = 0; q < 4; ++q) {
      int ci = q * 256 + tid;            // 16B chunk index, 0..1023
      int r = ci >> 3, c = ci & 7;
      int ldst = (q * 256 + wave * 64) * 8;   // uniform per wave (elems)
      gload_lds16(Ab + (size_t)r * K1 + kt * 64 + c * 8, lA + ldst);
      gload_lds16(Bb + (size_t)r * K1 + kt * 64 + c * 8, lB + ldst);
    }
    __syncthreads();
#pragma unroll
    for (int kk = 0; kk < 2; ++kk) {
      bf16x8 af[4], bfr[4];
#pragma unroll
      for (int m = 0; m < 4; ++m)
        af[m] = *reinterpret_cast<const bf16x8*>(&lA[(wm * 64 + m * 16 + lr) * 64 + kk * 32 + lk * 8]);
#pragma unroll
      for (int n = 0; n < 4; ++n)
        bfr[n] = *reinterpret_cast<const bf16x8*>(&lB[(wn * 64 + n * 16 + lr) * 64 + kk * 32 + lk * 8]);
#pragma unroll
      for (int m = 0; m < 4; ++m)
#pragma unroll
        for (int n = 0; n < 4; ++n)
          acc[m][n] = __builtin_amdgcn_mfma_f32_16x16x32_bf16(af[m], bfr[n], acc[m][n], 0, 0, 0);
    }
  }

  // epilogue: C/D layout col=lane&15, row=(lane>>4)*4+reg (m89-verified)
#pragma unroll
  for (int n = 0; n < 4; ++n) {
    int col = col0 + wn * 64 + n * 16 + lr;
#pragma unroll
    for (int m = 0; m < 4; ++m) {
#pragma unroll
      for (int v = 0; v < 4; ++v) {
        int row = row0 + wm * 64 + m * 16 + lk * 4 + v;
        C[(size_t)row * N1_PAD + col] = f2bf(acc[m][n][v]);
      }
    }
  }
}

// ============ GEMM2: grouped, out[M][4096](f32) with bias + head permutation ============
// XCD-chunked remap: all 32 blocks (8 groups x 4 N-tiles) of one M-tile run on
// the same XCD consecutively -> the 0.5 MB lat M-panel is read once from
// HBM/L3 and re-served from L2; U (1.9 MB) is L2-resident.
__global__ void gemm2_kernel(const u16* __restrict__ A,      // latents [M][1920]
                             const u16* __restrict__ Uall,   // packed [512][r_g] per group
                             const float* __restrict__ bias, // [8][512]
                             float* __restrict__ out) {      // [M][4096]
  const int tid  = threadIdx.x;
  const int wave = tid >> 6, lane = tid & 63;
  const int lr = lane & 15, lk = lane >> 4;
  const int wm = wave >> 1, wn = wave & 1;

  // 4096 wgs = 8 xcds * (16 M-tiles * (8 groups * 4 N-tiles))
  const int W   = blockIdx.x;
  const int xcd = W & 7, idx = W >> 3;      // idx 0..511
  const int mt  = (idx >> 5) + xcd * 16;    // 0..127
  const int rem = idx & 31;
  const int g   = rem >> 2;                 // 0..7
  const int nt  = rem & 3;                  // 0..3

  const int rank = c_RANK[g], off = c_OFF[g];
  __shared__ u16 lA[128 * 64];
  __shared__ u16 lB[128 * 64];
  const int row0 = mt * 128;
  const int col0 = nt * 128;                // within the group's 512 cols

  const u16* Ab = A + (size_t)row0 * N1_PAD + off;
  const u16* Bb = Uall + (size_t)512 * off + (size_t)col0 * rank;

  f32x4 acc[4][4] = {};

  const int nkt = rank >> 6;
  for (int kt = 0; kt < nkt; ++kt) {
    __syncthreads();
#pragma unroll
    for (int q = 0; q < 4; ++q) {
      int ci = q * 256 + tid;
      int r = ci >> 3, c = ci & 7;
      int ldst = (q * 256 + wave * 64) * 8;
      gload_lds16(Ab + (size_t)r * N1_PAD + kt * 64 + c * 8, lA + ldst);
      gload_lds16(Bb + (size_t)r * rank   + kt * 64 + c * 8, lB + ldst);
    }
    __syncthreads();
#pragma unroll
    for (int kk = 0; kk < 2; ++kk) {
      bf16x8 af[4], bfr[4];
#pragma unroll
      for (int m = 0; m < 4; ++m)
        af[m] = *reinterpret_cast<const bf16x8*>(&lA[(wm * 64 + m * 16 + lr) * 64 + kk * 32 + lk * 8]);
#pragma unroll
      for (int n = 0; n < 4; ++n)
        bfr[n] = *reinterpret_cast<const bf16x8*>(&lB[(wn * 64 + n * 16 + lr) * 64 + kk * 32 + lk * 8]);
#pragma unroll
      for (int m = 0; m < 4; ++m)
#pragma unroll
        for (int n = 0; n < 4; ++n)
          acc[m][n] = __builtin_amdgcn_mfma_f32_16x16x32_bf16(af[m], bfr[n], acc[m][n], 0, 0, 0);
    }
  }

#pragma unroll
  for (int n = 0; n < 4; ++n) {
    int cg = col0 + wn * 64 + n * 16 + lr;          // 0..511 within group
    int h  = (g << 2) + (cg >> 7);                  // computed head
    int oc = (c_FWD[h] << 7) | (cg & 127);          // permuted output column
    float bv = bias[(g << 9) + cg];
#pragma unroll
    for (int m = 0; m < 4; ++m) {
#pragma unroll
      for (int v = 0; v < 4; ++v) {
        int row = row0 + wm * 64 + m * 16 + lk * 4 + v;
        out[(size_t)row * 4096 + oc] = acc[m][n][v] + bv;
      }
    }
  }
}

extern "C" void kernel_launch(void* const* d_in, const int* in_sizes, int n_in,
                              void* d_out, int out_size, void* d_ws, size_t ws_size,
                              hipStream_t stream) {
  const float* hs = (const float*)d_in[0];
  const float* vt = (const float*)d_in[1];

  // workspace layout (all 16B-aligned); total ~205 MiB
  u16* hsb = (u16*)d_ws;                                // [16384][4096] bf16: 128 MiB
  u16* vtb = hsb + (size_t)M_TOT * K1;                  // [1920][4096]  bf16: 15 MiB
  u16* lat = vtb + (size_t)N1_PAD * K1;                 // [16384][1920] bf16: 60 MiB
  u16* ub  = lat + (size_t)M_TOT * N1_PAD;              // packed U: [512][r_g] x8: 1.9 MiB
  float* bias = (float*)(ub + (size_t)512 * N1_REAL);   // [8][512] f32

  // 1) convert hidden_states to bf16
  {
    int n4 = M_TOT * K1 / 4;  // 16,777,216 float4s
    cvt_f32_bf16<<<n4 / 256, 256, 0, stream>>>(hs, hsb, n4);
  }
  // 2) convert + zero-pad VT_w
  {
    int n4 = N1_PAD * K1 / 4;
    cvt_pad_vt<<<(n4 + 255) / 256, 256, 0, stream>>>(vt, vtb);
  }
  // 3) pack all U_w + biases in one launch
  {
    GroupPtrs gp;
    for (int g = 0; g < 8; ++g) {
      gp.uw[g] = (const float*)d_in[2 + 2 * g];
      gp.ub[g] = (const float*)d_in[3 + 2 * g];
    }
    // max group: 512*384/4 = 49152 float4 -> 192 blocks of 256
    pack_u_bias<<<dim3(192, 8), 256, 0, stream>>>(gp, ub, bias);
  }

  // 4) GEMM1: latents = hs @ VT^T   (1-D grid, XCD-chunked decode in-kernel)
  gemm1_kernel<<<dim3(1920), 256, 0, stream>>>(hsb, vtb, lat);

  // 5) GEMM2: grouped low-rank up-proj + bias + head permutation (1-D grid)
  gemm2_kernel<<<dim3(4096), 256, 0, stream>>>(lat, ub, bias, (float*)d_out);
}